// Round 2
// baseline (455.545 us; speedup 1.0000x reference)
//
#include <hip/hip_runtime.h>
#include <hip/hip_bf16.h>

// LightGCN on MI355X. R14: direct atomic counting-sort CSR build + unroll-8 SpMM.
// R13 post-mortem: p2 swizzle+ILP worked (left top-5; 280->257). New leader:
// spmm_csr 41 us, FETCH 119 MB. Analysis: gather traffic floor = nXCD x
// touched-cols x 128 B ~ 100-150 MB (embA 19.2 MB >> 4 MB per-XCD L2; the
// 13.3x per-row reuse spreads over 8 XCDs -> per-XCD reuse only ~1.7x).
// Col-band reordering can NOT beat this floor (cross-XCD reuse lands in L3
// either way). So: (a) unroll 8 in spmm_row to test latency- vs
// queue-saturation (VALU 27%, occ 61% suggests MLP headroom);
// (b) replace the deterministic bucket CSR build (p1+scanA+scanB+p2+bsort,
//     est ~60-70 us, incl. part 16 MB r+w and bsort's 2 full passes) with a
//     textbook counting sort: global-atomic hist -> 3-dispatch scan ->
//     atomic-cursor scatter. 2M atomics over 150K addrs = ~13/addr, mild.
//     Intra-row edge order becomes nondeterministic; SpMM sums are
//     order-independent up to f32 rounding (bf16 ulp; tolerance-based check).
// Predicted: scatter ~15-20 us; bsort/scanA/p2 gone; spmm 41->~30 if
// latency-bound (FETCH flat); total 257 -> ~215-230.
// Falsification: scatter >30 us -> L2 atomic-return wall -> revert to
// hierarchical deterministic build.
//
// d_ws (4B units): embA bf16[totalF] | embB bf16[totalF] | Ub[B*64] |
//   Ib[B*64] | pairs int2[E] | rowPtr[N+1] | cur[N] | blkSum[256] |
//   flag2[N] | flagB[N]   (~58 MB)

#define EMB 64
#define BP 2048         // edge-segment blocks for hist/scatter

__device__ __forceinline__ float bf2f_lo(unsigned int u) {
    return __int_as_float((int)(u << 16));
}
__device__ __forceinline__ float bf2f_hi(unsigned int u) {
    return __int_as_float((int)(u & 0xFFFF0000u));
}
__device__ __forceinline__ float bf2f(unsigned short u) {
    return __int_as_float(((int)u) << 16);
}
__device__ __forceinline__ unsigned short f2bf(float f) {
    union { float f; unsigned int i; } v;
    v.f = f;
    unsigned int lsb = (v.i >> 16) & 1;
    v.i += 0x7fffu + lsb;          // round-to-nearest-even
    return (unsigned short)(v.i >> 16);
}
__device__ __forceinline__ unsigned int pack2(float a, float b) {
    return (unsigned int)f2bf(a) | ((unsigned int)f2bf(b) << 16);
}

// inclusive scan across a 64-lane wave (no barriers)
__device__ __forceinline__ int wave_iscan(int v) {
    int lane = threadIdx.x & 63;
#pragma unroll
    for (int off = 1; off < 64; off <<= 1) {
        int x = __shfl_up(v, off, 64);
        if (lane >= off) v += x;
    }
    return v;
}

// ---------- zero hist (incl. sentinel slot) ----------
__global__ void ALGN_zero(int* __restrict__ p, int n) {
    int t = blockIdx.x * blockDim.x + threadIdx.x;
    if (t < n) p[t] = 0;
}

// ---------- fused: init (concat->bf16, zero flags) | hist (row counts) ----
// blocks [0, initBlocks): init; [initBlocks, initBlocks+BP): hist.
__global__ void ALGN_init_hist(const float4* __restrict__ ue, const float4* __restrict__ ie,
                               uint4* __restrict__ emb, int* __restrict__ flags, int nFlags,
                               int nUser8, int n8, int initBlocks,
                               const int* __restrict__ rows, int* __restrict__ hist,
                               int nE, int seg) {
    if (blockIdx.x < initBlocks) {
        int t = blockIdx.x * blockDim.x + threadIdx.x;
        if (t < nFlags) flags[t] = 0;
        if (t >= n8) return;
        float4 a, b;
        if (t < nUser8) { a = ue[2 * t]; b = ue[2 * t + 1]; }
        else           { a = ie[2 * (t - nUser8)]; b = ie[2 * (t - nUser8) + 1]; }
        uint4 o;
        o.x = pack2(a.x, a.y);
        o.y = pack2(a.z, a.w);
        o.z = pack2(b.x, b.y);
        o.w = pack2(b.z, b.w);
        emb[t] = o;
    } else {
        int blk = blockIdx.x - initBlocks;
        int beg = blk * seg, end = min(beg + seg, nE);
        for (int e = beg + (threadIdx.x << 2); e < end; e += (blockDim.x << 2)) {
            if (e + 4 <= end) {
                int4 r = *(const int4*)(rows + e);
                atomicAdd(&hist[r.x], 1);
                atomicAdd(&hist[r.y], 1);
                atomicAdd(&hist[r.z], 1);
                atomicAdd(&hist[r.w], 1);
            } else {
                for (int k = e; k < end; ++k) atomicAdd(&hist[rows[k]], 1);
            }
        }
    }
}

// ---------- scan1: per-1024-chunk exclusive scan of hist (in-place) -------
__global__ void ALGN_scan1(int* __restrict__ hist, int* __restrict__ blkSum, int n) {
    __shared__ int wsum[16];
    int t = threadIdx.x, wid = t >> 6;
    int i = blockIdx.x * 1024 + t;
    int v = (i < n) ? hist[i] : 0;
    int isc = wave_iscan(v);
    if ((t & 63) == 63) wsum[wid] = isc;
    __syncthreads();
    if (t < 64) {
        int x = (t < 16) ? wsum[t] : 0;
        x = wave_iscan(x);
        if (t < 16) wsum[t] = x;
    }
    __syncthreads();
    int incl = isc + ((wid > 0) ? wsum[wid - 1] : 0);
    if (i < n) hist[i] = incl - v;               // chunk-local exclusive
    if (t == 1023) blkSum[blockIdx.x] = incl;    // chunk total
}

// ---------- scan2: exclusive scan of chunk totals (in-place, nB<=256) -----
__global__ void ALGN_scan2(int* __restrict__ blkSum, int nB) {
    __shared__ int wsum[4];
    int t = threadIdx.x, wid = t >> 6;
    int v = (t < nB) ? blkSum[t] : 0;
    int isc = wave_iscan(v);
    if ((t & 63) == 63) wsum[wid] = isc;
    __syncthreads();
    if (t < 64) {
        int x = (t < 4) ? wsum[t] : 0;
        x = wave_iscan(x);
        if (t < 4) wsum[t] = x;
    }
    __syncthreads();
    if (t < nB) blkSum[t] = isc + ((wid > 0) ? wsum[wid - 1] : 0) - v;
}

// ---------- scan3: add chunk base; hist becomes rowPtr; copy cursors ------
__global__ void ALGN_scan3(int* __restrict__ hist, const int* __restrict__ blkSum,
                           int* __restrict__ cur, int n, int nE) {
    int i = blockIdx.x * 1024 + threadIdx.x;
    if (i < n) {
        int v = hist[i] + blkSum[blockIdx.x];
        hist[i] = v;
        cur[i] = v;
    }
    if (i == 0) hist[n] = nE;                    // sentinel
}

// ---------- scatter: pairs[atomic cursor] = (col, val) --------------------
__global__ void ALGN_scatter(const int* __restrict__ rows, const int* __restrict__ cols,
                             const float* __restrict__ vals, int* __restrict__ cur,
                             int2* __restrict__ pairs, int nE, int seg) {
    int blk = blockIdx.x;
    int beg = blk * seg, end = min(beg + seg, nE);
    for (int e = beg + (threadIdx.x << 2); e < end; e += (blockDim.x << 2)) {
        if (e + 4 <= end) {
            int4   r = *(const int4*)(rows + e);
            int4   c = *(const int4*)(cols + e);
            float4 v = *(const float4*)(vals + e);
            int p0 = atomicAdd(&cur[r.x], 1);
            int p1 = atomicAdd(&cur[r.y], 1);
            int p2 = atomicAdd(&cur[r.z], 1);
            int p3 = atomicAdd(&cur[r.w], 1);
            pairs[p0] = make_int2(c.x, __float_as_int(v.x));
            pairs[p1] = make_int2(c.y, __float_as_int(v.y));
            pairs[p2] = make_int2(c.z, __float_as_int(v.z));
            pairs[p3] = make_int2(c.w, __float_as_int(v.w));
        } else {
            for (int k = e; k < end; ++k) {
                int pos = atomicAdd(&cur[rows[k]], 1);
                pairs[pos] = make_int2(cols[k], __float_as_int(vals[k]));
            }
        }
    }
}

// ---------- fused: mark2 (demand flags) | gather_set (layer 0) ----------
// blocks [0, markBlocks): mark2 (16 lanes/batch row);
// [markBlocks, markBlocks+gsBlocks): gather_set.
__global__ void ALGN_mark_gather(const int* __restrict__ rowPtr, const int2* __restrict__ pairs,
                                 const int* __restrict__ users, const int* __restrict__ items,
                                 int* __restrict__ flag2, int* __restrict__ flagB,
                                 int batch, int nUser, int markBlocks,
                                 const unsigned short* __restrict__ emb,
                                 float* __restrict__ U, float* __restrict__ I) {
    if (blockIdx.x < markBlocks) {
        int tid = blockIdx.x * blockDim.x + threadIdx.x;
        int idx = tid >> 4;
        int ln  = tid & 15;
        if (idx >= 2 * batch) return;
        int row = (idx < batch) ? users[idx] : (nUser + items[idx - batch]);
        if (ln == 0) { flagB[row] = 1; flag2[row] = 1; }
        int beg = rowPtr[row], end = rowPtr[row + 1];
        for (int j = beg + ln; j < end; j += 16) flag2[pairs[j].x] = 1;
    } else {
        int t = (blockIdx.x - markBlocks) * blockDim.x + threadIdx.x;
        if (t >= batch * EMB) return;
        int b = t >> 6, c = t & 63;
        U[t] = bf2f(emb[users[b] * EMB + c]) * 0.25f;
        I[t] = bf2f(emb[(nUser + items[b]) * EMB + c]) * 0.25f;
    }
}

// ---------- SpMM row body: 8 lanes/row, uint4 = 8 bf16/lane, unroll x8 ----
__device__ __forceinline__ void acc8(float& s0, float& s1, float& s2, float& s3,
                                     float& s4, float& s5, float& s6, float& s7,
                                     float v, uint4 x) {
    s0 += v * bf2f_lo(x.x); s1 += v * bf2f_hi(x.x);
    s2 += v * bf2f_lo(x.y); s3 += v * bf2f_hi(x.y);
    s4 += v * bf2f_lo(x.z); s5 += v * bf2f_hi(x.z);
    s6 += v * bf2f_lo(x.w); s7 += v * bf2f_hi(x.w);
}

__device__ __forceinline__ void spmm_row(const uint4* __restrict__ cur,
                                         uint4* __restrict__ next,
                                         const int* __restrict__ rowPtr,
                                         const int2* __restrict__ pairs,
                                         int row, int fl) {
    int beg = rowPtr[row];
    int end = rowPtr[row + 1];
    float s0 = 0.f, s1 = 0.f, s2 = 0.f, s3 = 0.f;
    float s4 = 0.f, s5 = 0.f, s6 = 0.f, s7 = 0.f;
    int j = beg;
    for (; j + 8 <= end; j += 8) {
        int2 e0 = pairs[j + 0];
        int2 e1 = pairs[j + 1];
        int2 e2 = pairs[j + 2];
        int2 e3 = pairs[j + 3];
        int2 e4 = pairs[j + 4];
        int2 e5 = pairs[j + 5];
        int2 e6 = pairs[j + 6];
        int2 e7 = pairs[j + 7];
        uint4 x0 = cur[(size_t)e0.x * 8 + fl];
        uint4 x1 = cur[(size_t)e1.x * 8 + fl];
        uint4 x2 = cur[(size_t)e2.x * 8 + fl];
        uint4 x3 = cur[(size_t)e3.x * 8 + fl];
        uint4 x4 = cur[(size_t)e4.x * 8 + fl];
        uint4 x5 = cur[(size_t)e5.x * 8 + fl];
        uint4 x6 = cur[(size_t)e6.x * 8 + fl];
        uint4 x7 = cur[(size_t)e7.x * 8 + fl];
        acc8(s0, s1, s2, s3, s4, s5, s6, s7, __int_as_float(e0.y), x0);
        acc8(s0, s1, s2, s3, s4, s5, s6, s7, __int_as_float(e1.y), x1);
        acc8(s0, s1, s2, s3, s4, s5, s6, s7, __int_as_float(e2.y), x2);
        acc8(s0, s1, s2, s3, s4, s5, s6, s7, __int_as_float(e3.y), x3);
        acc8(s0, s1, s2, s3, s4, s5, s6, s7, __int_as_float(e4.y), x4);
        acc8(s0, s1, s2, s3, s4, s5, s6, s7, __int_as_float(e5.y), x5);
        acc8(s0, s1, s2, s3, s4, s5, s6, s7, __int_as_float(e6.y), x6);
        acc8(s0, s1, s2, s3, s4, s5, s6, s7, __int_as_float(e7.y), x7);
    }
    for (; j + 4 <= end; j += 4) {
        int2 e0 = pairs[j + 0];
        int2 e1 = pairs[j + 1];
        int2 e2 = pairs[j + 2];
        int2 e3 = pairs[j + 3];
        uint4 x0 = cur[(size_t)e0.x * 8 + fl];
        uint4 x1 = cur[(size_t)e1.x * 8 + fl];
        uint4 x2 = cur[(size_t)e2.x * 8 + fl];
        uint4 x3 = cur[(size_t)e3.x * 8 + fl];
        acc8(s0, s1, s2, s3, s4, s5, s6, s7, __int_as_float(e0.y), x0);
        acc8(s0, s1, s2, s3, s4, s5, s6, s7, __int_as_float(e1.y), x1);
        acc8(s0, s1, s2, s3, s4, s5, s6, s7, __int_as_float(e2.y), x2);
        acc8(s0, s1, s2, s3, s4, s5, s6, s7, __int_as_float(e3.y), x3);
    }
    for (; j < end; ++j) {
        int2 e = pairs[j];
        uint4 x = cur[(size_t)e.x * 8 + fl];
        acc8(s0, s1, s2, s3, s4, s5, s6, s7, __int_as_float(e.y), x);
    }
    uint4 o;
    o.x = pack2(s0, s1);
    o.y = pack2(s2, s3);
    o.z = pack2(s4, s5);
    o.w = pack2(s6, s7);
    next[(size_t)row * 8 + fl] = o;
}

__global__ void ALGN_spmm_csr(const uint4* __restrict__ cur, uint4* __restrict__ next,
                              const int* __restrict__ rowPtr, const int2* __restrict__ pairs,
                              int nNodes) {
    int tid = blockIdx.x * blockDim.x + threadIdx.x;
    int row = tid >> 3;
    int fl  = tid & 7;
    if (row >= nNodes) return;
    spmm_row(cur, next, rowPtr, pairs, row, fl);
}

__global__ void ALGN_spmm_flag(const uint4* __restrict__ cur, uint4* __restrict__ next,
                               const int* __restrict__ rowPtr, const int2* __restrict__ pairs,
                               const int* __restrict__ flag, int nNodes) {
    int tid = blockIdx.x * blockDim.x + threadIdx.x;
    int row = tid >> 3;
    int fl  = tid & 7;
    if (row >= nNodes) return;
    if (!flag[row]) return;
    spmm_row(cur, next, rowPtr, pairs, row, fl);
}

// ---------- batch gather-accumulate (layer mean 0.25 folded per side) -----
__global__ void ALGN_gather_add(const unsigned short* __restrict__ emb,
                                const int* __restrict__ users, const int* __restrict__ items,
                                float* __restrict__ U, float* __restrict__ I,
                                int batch, int nUser) {
    int t = blockIdx.x * blockDim.x + threadIdx.x;
    if (t >= batch * EMB) return;
    int b = t >> 6, c = t & 63;
    U[t] += bf2f(emb[users[b] * EMB + c]) * 0.25f;
    I[t] += bf2f(emb[(nUser + items[b]) * EMB + c]) * 0.25f;
}

// ---------- sigmoid(U @ I^T): 32x32 tile, 256 threads, 2x2 out/thread ----
__global__ void ALGN_gemm_sigmoid(const float* __restrict__ U, const float* __restrict__ I,
                                  float* __restrict__ out, int B) {
    __shared__ float su[32][EMB + 1];
    __shared__ float si[32][EMB + 1];
    int tx = threadIdx.x, ty = threadIdx.y;     // 16x16
    int row0 = blockIdx.y * 32, col0 = blockIdx.x * 32;
    int tid = ty * 16 + tx;
    for (int k = tid; k < 32 * EMB; k += 256) {
        int r = k >> 6, c = k & 63;
        su[r][c] = U[(row0 + r) * EMB + c];
        si[r][c] = I[(col0 + r) * EMB + c];
    }
    __syncthreads();
    float s00 = 0.f, s01 = 0.f, s10 = 0.f, s11 = 0.f;
#pragma unroll
    for (int k = 0; k < EMB; ++k) {
        float a0 = su[2 * ty][k],     a1 = su[2 * ty + 1][k];
        float b0 = si[2 * tx][k],     b1 = si[2 * tx + 1][k];
        s00 += a0 * b0; s01 += a0 * b1;
        s10 += a1 * b0; s11 += a1 * b1;
    }
    int r0 = row0 + 2 * ty, c0 = col0 + 2 * tx;
    out[(size_t)r0 * B + c0]           = 1.f / (1.f + __expf(-s00));
    out[(size_t)r0 * B + c0 + 1]       = 1.f / (1.f + __expf(-s01));
    out[(size_t)(r0 + 1) * B + c0]     = 1.f / (1.f + __expf(-s10));
    out[(size_t)(r0 + 1) * B + c0 + 1] = 1.f / (1.f + __expf(-s11));
}

extern "C" void kernel_launch(void* const* d_in, const int* in_sizes, int n_in,
                              void* d_out, int out_size, void* d_ws, size_t ws_size,
                              hipStream_t stream) {
    const float* user_emb = (const float*)d_in[0];
    const float* item_emb = (const float*)d_in[1];
    const float* adj_vals = (const float*)d_in[2];
    const int*   adj_rows = (const int*)d_in[3];
    const int*   adj_cols = (const int*)d_in[4];
    const int*   users    = (const int*)d_in[5];
    const int*   items    = (const int*)d_in[6];
    float* out = (float*)d_out;

    const int nUserF = in_sizes[0];
    const int nItemF = in_sizes[1];
    const int nEdges = in_sizes[2];
    const int batch  = in_sizes[5];
    const int nUser  = nUserF / EMB;
    const int totalF = nUserF + nItemF;
    const int nNodes = totalF / EMB;
    const int n8     = totalF / 8;
    // seg rounded to x4 so int4/float4 edge loads are 16B-aligned
    const int seg    = (((nEdges + BP - 1) / BP) + 3) & ~3;   // 980

    unsigned short* embA = (unsigned short*)d_ws;
    unsigned short* embB = embA + totalF;
    float* Ub = (float*)(embB + totalF);
    float* Ib = Ub + (size_t)batch * EMB;
    int2*  pairs  = (int2*)(Ib + (size_t)batch * EMB);
    int*   rowPtr = (int*)(pairs + nEdges);          // doubles as hist
    int*   cur    = rowPtr + (nNodes + 1);
    int*   blkSum = cur + nNodes;
    int*   flag2  = blkSum + 256;
    int*   flagB  = flag2 + nNodes;

    // ---- zero hist (incl. sentinel) ----
    ALGN_zero<<<(nNodes + 1 + 255) / 256, 256, 0, stream>>>(rowPtr, nNodes + 1);

    // ---- fused init | hist ----
    const int initBlocks = (n8 + 255) / 256;         // covers n8 and 2*nNodes flags
    ALGN_init_hist<<<initBlocks + BP, 256, 0, stream>>>(
        (const float4*)user_emb, (const float4*)item_emb, (uint4*)embA,
        flag2, 2 * nNodes, nUserF / 8, n8, initBlocks,
        adj_rows, rowPtr, nEdges, seg);

    // ---- rowPtr = exclusive scan of hist; cur = copy ----
    const int nScanB = (nNodes + 1023) / 1024;       // 147
    ALGN_scan1<<<nScanB, 1024, 0, stream>>>(rowPtr, blkSum, nNodes);
    ALGN_scan2<<<1, 256, 0, stream>>>(blkSum, nScanB);
    ALGN_scan3<<<nScanB, 1024, 0, stream>>>(rowPtr, blkSum, cur, nNodes, nEdges);

    // ---- scatter into row-grouped pairs ----
    ALGN_scatter<<<BP, 256, 0, stream>>>(adj_rows, adj_cols, adj_vals,
                                         cur, pairs, nEdges, seg);

    // ---- fused mark2 | gather_set ----
    const int markBlocks = (2 * batch * 16 + 255) / 256;
    const int gsBlocks   = (batch * EMB + 255) / 256;
    ALGN_mark_gather<<<markBlocks + gsBlocks, 256, 0, stream>>>(
        rowPtr, pairs, users, items, flag2, flagB, batch, nUser, markBlocks,
        embA, Ub, Ib);

    const int fullBlocks = (nNodes * 8 + 255) / 256;

    // ---- layer 1: full ----
    ALGN_spmm_csr<<<fullBlocks, 256, 0, stream>>>(
        (const uint4*)embA, (uint4*)embB, rowPtr, pairs, nNodes);
    ALGN_gather_add<<<(batch * EMB + 255) / 256, 256, 0, stream>>>(
        embB, users, items, Ub, Ib, batch, nUser);

    // ---- layer 2: S2 rows only ----
    ALGN_spmm_flag<<<fullBlocks, 256, 0, stream>>>(
        (const uint4*)embB, (uint4*)embA, rowPtr, pairs, flag2, nNodes);
    ALGN_gather_add<<<(batch * EMB + 255) / 256, 256, 0, stream>>>(
        embA, users, items, Ub, Ib, batch, nUser);

    // ---- layer 3: batch rows only ----
    ALGN_spmm_flag<<<fullBlocks, 256, 0, stream>>>(
        (const uint4*)embA, (uint4*)embB, rowPtr, pairs, flagB, nNodes);
    ALGN_gather_add<<<(batch * EMB + 255) / 256, 256, 0, stream>>>(
        embB, users, items, Ub, Ib, batch, nUser);

    dim3 gg(batch / 32, batch / 32);
    dim3 gb(16, 16);
    ALGN_gemm_sigmoid<<<gg, gb, 0, stream>>>(Ub, Ib, out, batch);
}

// Round 3
// 265.141 us; speedup vs baseline: 1.7181x; 1.7181x over previous
//
#include <hip/hip_runtime.h>
#include <hip/hip_bf16.h>

// LightGCN on MI355X. R15: revert to R13's deterministic hierarchical CSR
// build (proven 257 us); keep ONLY the unroll-8 spmm_row from R14.
// R14 post-mortem: global-atomic counting-sort scatter = 178 us, WRITE
// 125 MB = 7.8x ideal (vs R13 p2's 1.4x). Mechanism: global per-row cursor
// -> consecutive writes to a row's region come from arbitrary blocks on
// arbitrary XCDs at arbitrary times -> every 8B write is a partial-line
// fill+evict, plus atomic-return serialization (VALU 0.3%). R13's two-level
// build (LDS cursors per bucket, bucket-grouped part, XCD-swizzled
// segments) exists precisely to bound write dispersion. LESSON: scattered
// writes must be locality-bounded by construction on this chip.
// R15 experiment: spmm_row unroll 4->8 (R13 counters: spmm 41 us, FETCH
// 119 MB, VALU 27%, occ 61% -> latency-bound on L3-served gather; embA
// 19.2 MB is L3-resident). Predict spmm 41->~32, VALUBusy ->~38%, FETCH
// flat; total ~245. Falsification: spmm flat -> fabric-queue-bound floor
// -> pivot to CSR-build cost (~60 us) next.
//
// d_ws (4B units): embA bf16[totalF] | embB bf16[totalF] | Ub[B*64] |
//   Ib[B*64] | pairs int2[E] | part int2[E] | rowPtr[N+1] |
//   blockHist[NBMAX*BP] | bucketTotal[NBMAX] | bucketBase[NBMAX+1] |
//   flag2[N] | flagB[N]   (~79 MB; 95 MB proven available)

#define EMB 64
#define BSZ 512         // rows per bucket (pow2: lr = r&511, u = r>>9)
#define NBMAX 512       // max buckets (actual: ceil(150000/512)=293)
#define BP 2048         // partition blocks (edge segments)

__device__ __forceinline__ float bf2f_lo(unsigned int u) {
    return __int_as_float((int)(u << 16));
}
__device__ __forceinline__ float bf2f_hi(unsigned int u) {
    return __int_as_float((int)(u & 0xFFFF0000u));
}
__device__ __forceinline__ float bf2f(unsigned short u) {
    return __int_as_float(((int)u) << 16);
}
__device__ __forceinline__ unsigned short f2bf(float f) {
    union { float f; unsigned int i; } v;
    v.f = f;
    unsigned int lsb = (v.i >> 16) & 1;
    v.i += 0x7fffu + lsb;          // round-to-nearest-even
    return (unsigned short)(v.i >> 16);
}
__device__ __forceinline__ unsigned int pack2(float a, float b) {
    return (unsigned int)f2bf(a) | ((unsigned int)f2bf(b) << 16);
}

// inclusive scan across a 64-lane wave (no barriers)
__device__ __forceinline__ int wave_iscan(int v) {
    int lane = threadIdx.x & 63;
#pragma unroll
    for (int off = 1; off < 64; off <<= 1) {
        int x = __shfl_up(v, off, 64);
        if (lane >= off) v += x;
    }
    return v;
}

// ---------- fused: init (concat->bf16, zero flags) | p1 (bucket hist) -----
// blocks [0, initBlocks): init; [initBlocks, initBlocks+BP): p1.
__global__ void ALGN_init_p1(const float4* __restrict__ ue, const float4* __restrict__ ie,
                             uint4* __restrict__ emb, int* __restrict__ flags, int nFlags,
                             int nUser8, int n8, int initBlocks,
                             const int* __restrict__ rows, int* __restrict__ blockHist,
                             int nE, int seg, int nBuckets) {
    __shared__ int h[NBMAX];
    if (blockIdx.x < initBlocks) {
        int t = blockIdx.x * blockDim.x + threadIdx.x;
        if (t < nFlags) flags[t] = 0;
        if (t >= n8) return;
        float4 a, b;
        if (t < nUser8) { a = ue[2 * t]; b = ue[2 * t + 1]; }
        else           { a = ie[2 * (t - nUser8)]; b = ie[2 * (t - nUser8) + 1]; }
        uint4 o;
        o.x = pack2(a.x, a.y);
        o.y = pack2(a.z, a.w);
        o.z = pack2(b.x, b.y);
        o.w = pack2(b.z, b.w);
        emb[t] = o;
    } else {
        int blk = blockIdx.x - initBlocks;
        for (int i = threadIdx.x; i < nBuckets; i += blockDim.x) h[i] = 0;
        __syncthreads();
        int beg = blk * seg, end = min(beg + seg, nE);
        for (int e = beg + threadIdx.x; e < end; e += blockDim.x)
            atomicAdd(&h[rows[e] >> 9], 1);
        __syncthreads();
        for (int u = threadIdx.x; u < nBuckets; u += blockDim.x)
            blockHist[u * BP + blk] = h[u];      // bucket-major
    }
}

// ---------- scanA: per bucket, exclusive scan across BP=2048 blocks -------
// blockDim = 1024, 2 elements/thread; wave-shfl scan.
__global__ void ALGN_scanA(int* __restrict__ blockHist, int* __restrict__ bucketTotal) {
    __shared__ int wsum[16];
    int b = blockIdx.x, t = threadIdx.x;
    int wid = t >> 6;
    int v0 = blockHist[b * BP + 2 * t];
    int v1 = blockHist[b * BP + 2 * t + 1];
    int s = v0 + v1;
    int isc = wave_iscan(s);
    if ((t & 63) == 63) wsum[wid] = isc;
    __syncthreads();
    if (t < 64) {
        int x = (t < 16) ? wsum[t] : 0;
        x = wave_iscan(x);
        if (t < 16) wsum[t] = x;
    }
    __syncthreads();
    int incl = isc + ((wid > 0) ? wsum[wid - 1] : 0);
    int excl = incl - s;
    blockHist[b * BP + 2 * t]     = excl;        // exclusive over blocks
    blockHist[b * BP + 2 * t + 1] = excl + v0;
    if (t == 1023) bucketTotal[b] = incl;
}

// ---------- scanB: exclusive scan of bucket totals -> bases ----------
// blockDim = 512 (8 waves).
__global__ void ALGN_scanB(const int* __restrict__ bucketTotal, int* __restrict__ bucketBase,
                           int nBuckets) {
    __shared__ int wsum[8];
    int t = threadIdx.x;
    int wid = t >> 6;
    int v = (t < nBuckets) ? bucketTotal[t] : 0;
    int isc = wave_iscan(v);
    if ((t & 63) == 63) wsum[wid] = isc;
    __syncthreads();
    if (t < 64) {
        int s = (t < 8) ? wsum[t] : 0;
        s = wave_iscan(s);
        if (t < 8) wsum[t] = s;
    }
    __syncthreads();
    int incl = isc + ((wid > 0) ? wsum[wid - 1] : 0);
    if (t < nBuckets) bucketBase[t] = incl - v;
    if (t == nBuckets - 1) bucketBase[nBuckets] = incl;
}

// ---------- partition pass 2: scatter packed records, LDS cursors ----------
// record: x = (localRow<<18) | col  (localRow<512, col<2^18), y = val bits
// blk = XCD-grouped swizzle of blockIdx (adjacent segments -> same XCD L2 so
// adjacent part-position runs merge before eviction); 4 consecutive edges
// per thread with int4/float4 loads (seg is x4-aligned -> 16B aligned).
__global__ void ALGN_p2(const int* __restrict__ rows, const int* __restrict__ cols,
                        const float* __restrict__ vals,
                        const int* __restrict__ blockHist, const int* __restrict__ bucketBase,
                        int2* __restrict__ part, int nE, int seg, int nBuckets) {
    __shared__ int cur[NBMAX];
    int blk = ((blockIdx.x & 7) * (BP >> 3)) + (blockIdx.x >> 3);
    for (int u = threadIdx.x; u < nBuckets; u += blockDim.x)
        cur[u] = bucketBase[u] + blockHist[u * BP + blk];
    __syncthreads();
    int beg = blk * seg, end = min(beg + seg, nE);
    for (int e = beg + (threadIdx.x << 2); e < end; e += (blockDim.x << 2)) {
        if (e + 4 <= end) {
            int4   r = *(const int4*)(rows + e);
            int4   c = *(const int4*)(cols + e);
            float4 v = *(const float4*)(vals + e);
            int p0 = atomicAdd(&cur[r.x >> 9], 1);
            int p1 = atomicAdd(&cur[r.y >> 9], 1);
            int p2 = atomicAdd(&cur[r.z >> 9], 1);
            int p3 = atomicAdd(&cur[r.w >> 9], 1);
            part[p0] = make_int2(((r.x & 511) << 18) | c.x, __float_as_int(v.x));
            part[p1] = make_int2(((r.y & 511) << 18) | c.y, __float_as_int(v.y));
            part[p2] = make_int2(((r.z & 511) << 18) | c.z, __float_as_int(v.z));
            part[p3] = make_int2(((r.w & 511) << 18) | c.w, __float_as_int(v.w));
        } else {
            for (int k = e; k < end; ++k) {
                int rr = rows[k];
                int pos = atomicAdd(&cur[rr >> 9], 1);
                part[pos] = make_int2(((rr & 511) << 18) | cols[k], __float_as_int(vals[k]));
            }
        }
    }
}

// ---------- per-bucket counting sort -> rowPtr + row-sorted pairs ----------
// blockDim = 1024; BSZ=512 local rows; wave-shfl scan.
__global__ void ALGN_bsort(const int2* __restrict__ part, const int* __restrict__ bucketBase,
                           int2* __restrict__ pairs, int* __restrict__ rowPtr,
                           int nNodes, int nBuckets, int nE) {
    __shared__ int st[BSZ];
    __shared__ int wsum[8];
    int b = blockIdx.x, t = threadIdx.x;
    int base = bucketBase[b], lim = bucketBase[b + 1];
    if (t < BSZ) st[t] = 0;
    __syncthreads();
    for (int j = base + t; j < lim; j += blockDim.x)
        atomicAdd(&st[part[j].x >> 18], 1);
    __syncthreads();
    int wid = t >> 6;
    int v = (t < BSZ) ? st[t] : 0;
    int isc = wave_iscan(v);
    if ((t & 63) == 63 && wid < 8) wsum[wid] = isc;
    __syncthreads();
    if (t < 64) {
        int s = (t < 8) ? wsum[t] : 0;
        s = wave_iscan(s);
        if (t < 8) wsum[t] = s;
    }
    __syncthreads();
    int excl = isc - v + ((wid > 0 && wid < 8) ? wsum[wid - 1] : 0);
    __syncthreads();
    if (t < BSZ) st[t] = excl;                   // exclusive starts / cursors
    int row = b * BSZ + t;
    if (t < BSZ && row < nNodes) rowPtr[row] = base + excl;
    if (b == nBuckets - 1 && t == 0) rowPtr[nNodes] = nE;
    __syncthreads();
    for (int j = base + t; j < lim; j += blockDim.x) {
        int2 p = part[j];
        int lr = p.x >> 18;
        int pos = base + atomicAdd(&st[lr], 1);
        pairs[pos] = make_int2(p.x & 0x3FFFF, p.y);
    }
}

// ---------- fused: mark2 (demand flags) | gather_set (layer 0) ----------
// blocks [0, markBlocks): mark2 (16 lanes/batch row);
// [markBlocks, markBlocks+gsBlocks): gather_set.
__global__ void ALGN_mark_gather(const int* __restrict__ rowPtr, const int2* __restrict__ pairs,
                                 const int* __restrict__ users, const int* __restrict__ items,
                                 int* __restrict__ flag2, int* __restrict__ flagB,
                                 int batch, int nUser, int markBlocks,
                                 const unsigned short* __restrict__ emb,
                                 float* __restrict__ U, float* __restrict__ I) {
    if (blockIdx.x < markBlocks) {
        int tid = blockIdx.x * blockDim.x + threadIdx.x;
        int idx = tid >> 4;
        int ln  = tid & 15;
        if (idx >= 2 * batch) return;
        int row = (idx < batch) ? users[idx] : (nUser + items[idx - batch]);
        if (ln == 0) { flagB[row] = 1; flag2[row] = 1; }
        int beg = rowPtr[row], end = rowPtr[row + 1];
        for (int j = beg + ln; j < end; j += 16) flag2[pairs[j].x] = 1;
    } else {
        int t = (blockIdx.x - markBlocks) * blockDim.x + threadIdx.x;
        if (t >= batch * EMB) return;
        int b = t >> 6, c = t & 63;
        U[t] = bf2f(emb[users[b] * EMB + c]) * 0.25f;
        I[t] = bf2f(emb[(nUser + items[b]) * EMB + c]) * 0.25f;
    }
}

// ---------- SpMM row body: 8 lanes/row, uint4 = 8 bf16/lane, unroll x8 ----
__device__ __forceinline__ void acc8(float& s0, float& s1, float& s2, float& s3,
                                     float& s4, float& s5, float& s6, float& s7,
                                     float v, uint4 x) {
    s0 += v * bf2f_lo(x.x); s1 += v * bf2f_hi(x.x);
    s2 += v * bf2f_lo(x.y); s3 += v * bf2f_hi(x.y);
    s4 += v * bf2f_lo(x.z); s5 += v * bf2f_hi(x.z);
    s6 += v * bf2f_lo(x.w); s7 += v * bf2f_hi(x.w);
}

__device__ __forceinline__ void spmm_row(const uint4* __restrict__ cur,
                                         uint4* __restrict__ next,
                                         const int* __restrict__ rowPtr,
                                         const int2* __restrict__ pairs,
                                         int row, int fl) {
    int beg = rowPtr[row];
    int end = rowPtr[row + 1];
    float s0 = 0.f, s1 = 0.f, s2 = 0.f, s3 = 0.f;
    float s4 = 0.f, s5 = 0.f, s6 = 0.f, s7 = 0.f;
    int j = beg;
    for (; j + 8 <= end; j += 8) {
        int2 e0 = pairs[j + 0];
        int2 e1 = pairs[j + 1];
        int2 e2 = pairs[j + 2];
        int2 e3 = pairs[j + 3];
        int2 e4 = pairs[j + 4];
        int2 e5 = pairs[j + 5];
        int2 e6 = pairs[j + 6];
        int2 e7 = pairs[j + 7];
        uint4 x0 = cur[(size_t)e0.x * 8 + fl];
        uint4 x1 = cur[(size_t)e1.x * 8 + fl];
        uint4 x2 = cur[(size_t)e2.x * 8 + fl];
        uint4 x3 = cur[(size_t)e3.x * 8 + fl];
        uint4 x4 = cur[(size_t)e4.x * 8 + fl];
        uint4 x5 = cur[(size_t)e5.x * 8 + fl];
        uint4 x6 = cur[(size_t)e6.x * 8 + fl];
        uint4 x7 = cur[(size_t)e7.x * 8 + fl];
        acc8(s0, s1, s2, s3, s4, s5, s6, s7, __int_as_float(e0.y), x0);
        acc8(s0, s1, s2, s3, s4, s5, s6, s7, __int_as_float(e1.y), x1);
        acc8(s0, s1, s2, s3, s4, s5, s6, s7, __int_as_float(e2.y), x2);
        acc8(s0, s1, s2, s3, s4, s5, s6, s7, __int_as_float(e3.y), x3);
        acc8(s0, s1, s2, s3, s4, s5, s6, s7, __int_as_float(e4.y), x4);
        acc8(s0, s1, s2, s3, s4, s5, s6, s7, __int_as_float(e5.y), x5);
        acc8(s0, s1, s2, s3, s4, s5, s6, s7, __int_as_float(e6.y), x6);
        acc8(s0, s1, s2, s3, s4, s5, s6, s7, __int_as_float(e7.y), x7);
    }
    for (; j + 4 <= end; j += 4) {
        int2 e0 = pairs[j + 0];
        int2 e1 = pairs[j + 1];
        int2 e2 = pairs[j + 2];
        int2 e3 = pairs[j + 3];
        uint4 x0 = cur[(size_t)e0.x * 8 + fl];
        uint4 x1 = cur[(size_t)e1.x * 8 + fl];
        uint4 x2 = cur[(size_t)e2.x * 8 + fl];
        uint4 x3 = cur[(size_t)e3.x * 8 + fl];
        acc8(s0, s1, s2, s3, s4, s5, s6, s7, __int_as_float(e0.y), x0);
        acc8(s0, s1, s2, s3, s4, s5, s6, s7, __int_as_float(e1.y), x1);
        acc8(s0, s1, s2, s3, s4, s5, s6, s7, __int_as_float(e2.y), x2);
        acc8(s0, s1, s2, s3, s4, s5, s6, s7, __int_as_float(e3.y), x3);
    }
    for (; j < end; ++j) {
        int2 e = pairs[j];
        uint4 x = cur[(size_t)e.x * 8 + fl];
        acc8(s0, s1, s2, s3, s4, s5, s6, s7, __int_as_float(e.y), x);
    }
    uint4 o;
    o.x = pack2(s0, s1);
    o.y = pack2(s2, s3);
    o.z = pack2(s4, s5);
    o.w = pack2(s6, s7);
    next[(size_t)row * 8 + fl] = o;
}

__global__ void ALGN_spmm_csr(const uint4* __restrict__ cur, uint4* __restrict__ next,
                              const int* __restrict__ rowPtr, const int2* __restrict__ pairs,
                              int nNodes) {
    int tid = blockIdx.x * blockDim.x + threadIdx.x;
    int row = tid >> 3;
    int fl  = tid & 7;
    if (row >= nNodes) return;
    spmm_row(cur, next, rowPtr, pairs, row, fl);
}

__global__ void ALGN_spmm_flag(const uint4* __restrict__ cur, uint4* __restrict__ next,
                               const int* __restrict__ rowPtr, const int2* __restrict__ pairs,
                               const int* __restrict__ flag, int nNodes) {
    int tid = blockIdx.x * blockDim.x + threadIdx.x;
    int row = tid >> 3;
    int fl  = tid & 7;
    if (row >= nNodes) return;
    if (!flag[row]) return;
    spmm_row(cur, next, rowPtr, pairs, row, fl);
}

// ---------- batch gather-accumulate (layer mean 0.25 folded per side) -----
__global__ void ALGN_gather_add(const unsigned short* __restrict__ emb,
                                const int* __restrict__ users, const int* __restrict__ items,
                                float* __restrict__ U, float* __restrict__ I,
                                int batch, int nUser) {
    int t = blockIdx.x * blockDim.x + threadIdx.x;
    if (t >= batch * EMB) return;
    int b = t >> 6, c = t & 63;
    U[t] += bf2f(emb[users[b] * EMB + c]) * 0.25f;
    I[t] += bf2f(emb[(nUser + items[b]) * EMB + c]) * 0.25f;
}

// ---------- sigmoid(U @ I^T): 32x32 tile, 256 threads, 2x2 out/thread ----
__global__ void ALGN_gemm_sigmoid(const float* __restrict__ U, const float* __restrict__ I,
                                  float* __restrict__ out, int B) {
    __shared__ float su[32][EMB + 1];
    __shared__ float si[32][EMB + 1];
    int tx = threadIdx.x, ty = threadIdx.y;     // 16x16
    int row0 = blockIdx.y * 32, col0 = blockIdx.x * 32;
    int tid = ty * 16 + tx;
    for (int k = tid; k < 32 * EMB; k += 256) {
        int r = k >> 6, c = k & 63;
        su[r][c] = U[(row0 + r) * EMB + c];
        si[r][c] = I[(col0 + r) * EMB + c];
    }
    __syncthreads();
    float s00 = 0.f, s01 = 0.f, s10 = 0.f, s11 = 0.f;
#pragma unroll
    for (int k = 0; k < EMB; ++k) {
        float a0 = su[2 * ty][k],     a1 = su[2 * ty + 1][k];
        float b0 = si[2 * tx][k],     b1 = si[2 * tx + 1][k];
        s00 += a0 * b0; s01 += a0 * b1;
        s10 += a1 * b0; s11 += a1 * b1;
    }
    int r0 = row0 + 2 * ty, c0 = col0 + 2 * tx;
    out[(size_t)r0 * B + c0]           = 1.f / (1.f + __expf(-s00));
    out[(size_t)r0 * B + c0 + 1]       = 1.f / (1.f + __expf(-s01));
    out[(size_t)(r0 + 1) * B + c0]     = 1.f / (1.f + __expf(-s10));
    out[(size_t)(r0 + 1) * B + c0 + 1] = 1.f / (1.f + __expf(-s11));
}

extern "C" void kernel_launch(void* const* d_in, const int* in_sizes, int n_in,
                              void* d_out, int out_size, void* d_ws, size_t ws_size,
                              hipStream_t stream) {
    const float* user_emb = (const float*)d_in[0];
    const float* item_emb = (const float*)d_in[1];
    const float* adj_vals = (const float*)d_in[2];
    const int*   adj_rows = (const int*)d_in[3];
    const int*   adj_cols = (const int*)d_in[4];
    const int*   users    = (const int*)d_in[5];
    const int*   items    = (const int*)d_in[6];
    float* out = (float*)d_out;

    const int nUserF = in_sizes[0];
    const int nItemF = in_sizes[1];
    const int nEdges = in_sizes[2];
    const int batch  = in_sizes[5];
    const int nUser  = nUserF / EMB;
    const int totalF = nUserF + nItemF;
    const int nNodes = totalF / EMB;
    const int n8     = totalF / 8;
    const int nBuckets = (nNodes + BSZ - 1) / BSZ;   // 293
    // seg rounded to x4 so p2's int4/float4 edge loads are 16B-aligned
    const int seg    = (((nEdges + BP - 1) / BP) + 3) & ~3;   // 980

    unsigned short* embA = (unsigned short*)d_ws;
    unsigned short* embB = embA + totalF;
    float* Ub = (float*)(embB + totalF);
    float* Ib = Ub + (size_t)batch * EMB;
    int2*  pairs = (int2*)(Ib + (size_t)batch * EMB);
    int2*  part  = pairs + nEdges;
    int*   rowPtr = (int*)(part + nEdges);
    int*   blockHist   = rowPtr + (nNodes + 1);
    int*   bucketTotal = blockHist + NBMAX * BP;
    int*   bucketBase  = bucketTotal + NBMAX;
    int*   flag2 = bucketBase + (NBMAX + 1);
    int*   flagB = flag2 + nNodes;

    // ---- fused init | p1 ----
    const int initBlocks = (n8 + 255) / 256;         // covers n8 and 2*nNodes flags
    ALGN_init_p1<<<initBlocks + BP, 256, 0, stream>>>(
        (const float4*)user_emb, (const float4*)item_emb, (uint4*)embA,
        flag2, 2 * nNodes, nUserF / 8, n8, initBlocks,
        adj_rows, blockHist, nEdges, seg, nBuckets);

    // ---- deterministic CSR build ----
    ALGN_scanA<<<nBuckets, 1024, 0, stream>>>(blockHist, bucketTotal);
    ALGN_scanB<<<1, 512, 0, stream>>>(bucketTotal, bucketBase, nBuckets);
    ALGN_p2<<<BP, 256, 0, stream>>>(adj_rows, adj_cols, adj_vals,
                                    blockHist, bucketBase, part, nEdges, seg, nBuckets);
    ALGN_bsort<<<nBuckets, 1024, 0, stream>>>(part, bucketBase, pairs, rowPtr,
                                              nNodes, nBuckets, nEdges);

    // ---- fused mark2 | gather_set ----
    const int markBlocks = (2 * batch * 16 + 255) / 256;
    const int gsBlocks   = (batch * EMB + 255) / 256;
    ALGN_mark_gather<<<markBlocks + gsBlocks, 256, 0, stream>>>(
        rowPtr, pairs, users, items, flag2, flagB, batch, nUser, markBlocks,
        embA, Ub, Ib);

    const int fullBlocks = (nNodes * 8 + 255) / 256;

    // ---- layer 1: full ----
    ALGN_spmm_csr<<<fullBlocks, 256, 0, stream>>>(
        (const uint4*)embA, (uint4*)embB, rowPtr, pairs, nNodes);
    ALGN_gather_add<<<(batch * EMB + 255) / 256, 256, 0, stream>>>(
        embB, users, items, Ub, Ib, batch, nUser);

    // ---- layer 2: S2 rows only ----
    ALGN_spmm_flag<<<fullBlocks, 256, 0, stream>>>(
        (const uint4*)embB, (uint4*)embA, rowPtr, pairs, flag2, nNodes);
    ALGN_gather_add<<<(batch * EMB + 255) / 256, 256, 0, stream>>>(
        embA, users, items, Ub, Ib, batch, nUser);

    // ---- layer 3: batch rows only ----
    ALGN_spmm_flag<<<fullBlocks, 256, 0, stream>>>(
        (const uint4*)embA, (uint4*)embB, rowPtr, pairs, flagB, nNodes);
    ALGN_gather_add<<<(batch * EMB + 255) / 256, 256, 0, stream>>>(
        embB, users, items, Ub, Ib, batch, nUser);

    dim3 gg(batch / 32, batch / 32);
    dim3 gb(16, 16);
    ALGN_gemm_sigmoid<<<gg, gb, 0, stream>>>(Ub, Ib, out, batch);
}

// Round 4
// 251.566 us; speedup vs baseline: 1.8108x; 1.0540x over previous
//
#include <hip/hip_runtime.h>
#include <hip/hip_bf16.h>

// LightGCN on MI355X. R16: dispatch-chain slim-down, 13 -> 8 dispatches.
// R15 post-mortem: unroll-8 FALSIFIED the spmm latency theory: occupancy
// 61->41% (VGPR 32->48) with time flat at 42 us, FETCH flat 115.7 MB.
// Runtime invariant to 1.5x resident waves = throughput-bound on the
// random-128B-line gather path (~3 TB/s fabric/L3 ceiling), and traffic is
// at the per-XCD unique-line floor (~124 MB model vs 115 measured).
// spmm_csr is DONE: revert to unroll-4 (proven 41 us, 32 VGPR), stop.
// Remaining ~215 us is 12 mid/small dispatches + gaps -> structural cuts:
//  (1) static CAP=8192 bucket regions in part/pairs (mean 6827, sd 83 ->
//      +16sigma safe) -> scanB + bucketBase GONE; bsort range from
//      bucketTotal; explicit rowPtr/rowEnd (CSR-with-gaps).
//  (2) mark2|gather_set fused into layer-1 spmm dispatch (block ranges;
//      outputs consumed only by later dispatches).
//  (3) gather_add L1/L2 fused into the NEXT spmm dispatch; gather_add L3
//      fused into gemm tile-load (bitwise-identical f32 math).
//  (4) layer-3 spmm over users/items list directly (dup rows write
//      identical bytes = benign) -> flagB + 150K-row flag scan GONE.
// Predicted: l1fuse ~43 us / FETCH ~116 MB / occ ~60%; total 265 -> ~230.
// Falsification: total ~255 -> gaps are tiny -> mid kernels dominate; the
// new top-5 will show exactly which (spmm pinned at 42 makes them visible).
//
// d_ws (4B units): embA bf16[totalF] | embB bf16[totalF] | Ub[B*64] |
//   Ib[B*64] | pairs int2[NB*CAP] | part int2[NB*CAP] | rowPtr[N] |
//   rowEnd[N] | blockHist[NBMAX*BP] | bucketTotal[NBMAX] | flag2[N]
//   (~84 MB; 95 MB proven available)

#define EMB 64
#define BSZ 512         // rows per bucket (pow2: lr = r&511, u = r>>9)
#define NBMAX 512       // max buckets (actual: ceil(150000/512)=293)
#define BP 2048         // partition blocks (edge segments)
#define CAP 8192        // static slots per bucket region (mean 6827 +16sd)

__device__ __forceinline__ float bf2f_lo(unsigned int u) {
    return __int_as_float((int)(u << 16));
}
__device__ __forceinline__ float bf2f_hi(unsigned int u) {
    return __int_as_float((int)(u & 0xFFFF0000u));
}
__device__ __forceinline__ float bf2f(unsigned short u) {
    return __int_as_float(((int)u) << 16);
}
__device__ __forceinline__ unsigned short f2bf(float f) {
    union { float f; unsigned int i; } v;
    v.f = f;
    unsigned int lsb = (v.i >> 16) & 1;
    v.i += 0x7fffu + lsb;          // round-to-nearest-even
    return (unsigned short)(v.i >> 16);
}
__device__ __forceinline__ unsigned int pack2(float a, float b) {
    return (unsigned int)f2bf(a) | ((unsigned int)f2bf(b) << 16);
}

// inclusive scan across a 64-lane wave (no barriers)
__device__ __forceinline__ int wave_iscan(int v) {
    int lane = threadIdx.x & 63;
#pragma unroll
    for (int off = 1; off < 64; off <<= 1) {
        int x = __shfl_up(v, off, 64);
        if (lane >= off) v += x;
    }
    return v;
}

// ---------- fused: init (concat->bf16, zero flag2) | p1 (bucket hist) -----
// blocks [0, initBlocks): init; [initBlocks, initBlocks+BP): p1.
__global__ void ALGN_init_p1(const float4* __restrict__ ue, const float4* __restrict__ ie,
                             uint4* __restrict__ emb, int* __restrict__ flags, int nFlags,
                             int nUser8, int n8, int initBlocks,
                             const int* __restrict__ rows, int* __restrict__ blockHist,
                             int nE, int seg, int nBuckets) {
    __shared__ int h[NBMAX];
    if (blockIdx.x < initBlocks) {
        int t = blockIdx.x * blockDim.x + threadIdx.x;
        if (t < nFlags) flags[t] = 0;
        if (t >= n8) return;
        float4 a, b;
        if (t < nUser8) { a = ue[2 * t]; b = ue[2 * t + 1]; }
        else           { a = ie[2 * (t - nUser8)]; b = ie[2 * (t - nUser8) + 1]; }
        uint4 o;
        o.x = pack2(a.x, a.y);
        o.y = pack2(a.z, a.w);
        o.z = pack2(b.x, b.y);
        o.w = pack2(b.z, b.w);
        emb[t] = o;
    } else {
        int blk = blockIdx.x - initBlocks;
        for (int i = threadIdx.x; i < nBuckets; i += blockDim.x) h[i] = 0;
        __syncthreads();
        int beg = blk * seg, end = min(beg + seg, nE);
        for (int e = beg + threadIdx.x; e < end; e += blockDim.x)
            atomicAdd(&h[rows[e] >> 9], 1);
        __syncthreads();
        for (int u = threadIdx.x; u < nBuckets; u += blockDim.x)
            blockHist[u * BP + blk] = h[u];      // bucket-major
    }
}

// ---------- scanA: per bucket, exclusive scan across BP=2048 blocks -------
// blockDim = 1024, 2 elements/thread; wave-shfl scan. Total -> bucketTotal.
__global__ void ALGN_scanA(int* __restrict__ blockHist, int* __restrict__ bucketTotal) {
    __shared__ int wsum[16];
    int b = blockIdx.x, t = threadIdx.x;
    int wid = t >> 6;
    int v0 = blockHist[b * BP + 2 * t];
    int v1 = blockHist[b * BP + 2 * t + 1];
    int s = v0 + v1;
    int isc = wave_iscan(s);
    if ((t & 63) == 63) wsum[wid] = isc;
    __syncthreads();
    if (t < 64) {
        int x = (t < 16) ? wsum[t] : 0;
        x = wave_iscan(x);
        if (t < 16) wsum[t] = x;
    }
    __syncthreads();
    int incl = isc + ((wid > 0) ? wsum[wid - 1] : 0);
    int excl = incl - s;
    blockHist[b * BP + 2 * t]     = excl;        // exclusive over blocks
    blockHist[b * BP + 2 * t + 1] = excl + v0;
    if (t == 1023) bucketTotal[b] = incl;
}

// ---------- partition pass 2: scatter packed records, LDS cursors ----------
// record: x = (localRow<<18) | col  (localRow<512, col<2^18), y = val bits
// Static bucket bases: bucket u's region = [u*CAP, u*CAP + total_u).
// blk = XCD-grouped swizzle (adjacent segments -> same XCD L2); 4 edges per
// thread with int4/float4 loads (seg x4-aligned).
__global__ void ALGN_p2(const int* __restrict__ rows, const int* __restrict__ cols,
                        const float* __restrict__ vals,
                        const int* __restrict__ blockHist,
                        int2* __restrict__ part, int nE, int seg, int nBuckets) {
    __shared__ int cur[NBMAX];
    int blk = ((blockIdx.x & 7) * (BP >> 3)) + (blockIdx.x >> 3);
    for (int u = threadIdx.x; u < nBuckets; u += blockDim.x)
        cur[u] = u * CAP + blockHist[u * BP + blk];
    __syncthreads();
    int beg = blk * seg, end = min(beg + seg, nE);
    for (int e = beg + (threadIdx.x << 2); e < end; e += (blockDim.x << 2)) {
        if (e + 4 <= end) {
            int4   r = *(const int4*)(rows + e);
            int4   c = *(const int4*)(cols + e);
            float4 v = *(const float4*)(vals + e);
            int p0 = atomicAdd(&cur[r.x >> 9], 1);
            int p1 = atomicAdd(&cur[r.y >> 9], 1);
            int p2 = atomicAdd(&cur[r.z >> 9], 1);
            int p3 = atomicAdd(&cur[r.w >> 9], 1);
            part[p0] = make_int2(((r.x & 511) << 18) | c.x, __float_as_int(v.x));
            part[p1] = make_int2(((r.y & 511) << 18) | c.y, __float_as_int(v.y));
            part[p2] = make_int2(((r.z & 511) << 18) | c.z, __float_as_int(v.z));
            part[p3] = make_int2(((r.w & 511) << 18) | c.w, __float_as_int(v.w));
        } else {
            for (int k = e; k < end; ++k) {
                int rr = rows[k];
                int pos = atomicAdd(&cur[rr >> 9], 1);
                part[pos] = make_int2(((rr & 511) << 18) | cols[k], __float_as_int(vals[k]));
            }
        }
    }
}

// ---------- per-bucket counting sort -> rowPtr/rowEnd + row-sorted pairs --
// blockDim = 1024; BSZ=512 local rows; wave-shfl scan. CAP-gapped layout.
__global__ void ALGN_bsort(const int2* __restrict__ part, const int* __restrict__ bucketTotal,
                           int2* __restrict__ pairs, int* __restrict__ rowPtr,
                           int* __restrict__ rowEnd, int nNodes) {
    __shared__ int st[BSZ];
    __shared__ int wsum[8];
    int b = blockIdx.x, t = threadIdx.x;
    int base = b * CAP;
    int lim  = base + bucketTotal[b];
    if (t < BSZ) st[t] = 0;
    __syncthreads();
    for (int j = base + t; j < lim; j += blockDim.x)
        atomicAdd(&st[part[j].x >> 18], 1);
    __syncthreads();
    int wid = t >> 6;
    int v = (t < BSZ) ? st[t] : 0;
    int isc = wave_iscan(v);
    if ((t & 63) == 63 && wid < 8) wsum[wid] = isc;
    __syncthreads();
    if (t < 64) {
        int s = (t < 8) ? wsum[t] : 0;
        s = wave_iscan(s);
        if (t < 8) wsum[t] = s;
    }
    __syncthreads();
    int excl = isc - v + ((wid > 0 && wid < 8) ? wsum[wid - 1] : 0);
    __syncthreads();
    if (t < BSZ) st[t] = excl;                   // exclusive starts / cursors
    int row = b * BSZ + t;
    if (t < BSZ && row < nNodes) {
        rowPtr[row] = base + excl;
        rowEnd[row] = base + excl + v;
    }
    __syncthreads();
    for (int j = base + t; j < lim; j += blockDim.x) {
        int2 p = part[j];
        int lr = p.x >> 18;
        int pos = base + atomicAdd(&st[lr], 1);
        pairs[pos] = make_int2(p.x & 0x3FFFF, p.y);
    }
}

// ---------- SpMM row body: 8 lanes/row, uint4 = 8 bf16/lane, unroll x4 ----
// (R13-proven: 41 us, 32 VGPR, occ 61%; unroll-8 was flat at half occ.)
__device__ __forceinline__ void acc8(float& s0, float& s1, float& s2, float& s3,
                                     float& s4, float& s5, float& s6, float& s7,
                                     float v, uint4 x) {
    s0 += v * bf2f_lo(x.x); s1 += v * bf2f_hi(x.x);
    s2 += v * bf2f_lo(x.y); s3 += v * bf2f_hi(x.y);
    s4 += v * bf2f_lo(x.z); s5 += v * bf2f_hi(x.z);
    s6 += v * bf2f_lo(x.w); s7 += v * bf2f_hi(x.w);
}

__device__ __forceinline__ void spmm_row(const uint4* __restrict__ cur,
                                         uint4* __restrict__ next,
                                         const int* __restrict__ rowPtr,
                                         const int* __restrict__ rowEnd,
                                         const int2* __restrict__ pairs,
                                         int row, int fl) {
    int beg = rowPtr[row];
    int end = rowEnd[row];
    float s0 = 0.f, s1 = 0.f, s2 = 0.f, s3 = 0.f;
    float s4 = 0.f, s5 = 0.f, s6 = 0.f, s7 = 0.f;
    int j = beg;
    for (; j + 4 <= end; j += 4) {
        int2 e0 = pairs[j + 0];
        int2 e1 = pairs[j + 1];
        int2 e2 = pairs[j + 2];
        int2 e3 = pairs[j + 3];
        uint4 x0 = cur[(size_t)e0.x * 8 + fl];
        uint4 x1 = cur[(size_t)e1.x * 8 + fl];
        uint4 x2 = cur[(size_t)e2.x * 8 + fl];
        uint4 x3 = cur[(size_t)e3.x * 8 + fl];
        acc8(s0, s1, s2, s3, s4, s5, s6, s7, __int_as_float(e0.y), x0);
        acc8(s0, s1, s2, s3, s4, s5, s6, s7, __int_as_float(e1.y), x1);
        acc8(s0, s1, s2, s3, s4, s5, s6, s7, __int_as_float(e2.y), x2);
        acc8(s0, s1, s2, s3, s4, s5, s6, s7, __int_as_float(e3.y), x3);
    }
    for (; j < end; ++j) {
        int2 e = pairs[j];
        uint4 x = cur[(size_t)e.x * 8 + fl];
        acc8(s0, s1, s2, s3, s4, s5, s6, s7, __int_as_float(e.y), x);
    }
    uint4 o;
    o.x = pack2(s0, s1);
    o.y = pack2(s2, s3);
    o.z = pack2(s4, s5);
    o.w = pack2(s6, s7);
    next[(size_t)row * 8 + fl] = o;
}

// ---------- fused layer 1: full spmm | mark2 | gather_set -----------------
// [0, spmmBlocks): full spmm embA->embB;
// [spmmBlocks, +markBlocks): mark flag2 = batch rows + neighbors;
// rest: gather layer-0 into U/I (0.25 folded).
__global__ void ALGN_l1fuse(const uint4* __restrict__ curE, uint4* __restrict__ nextE,
                            const int* __restrict__ rowPtr, const int* __restrict__ rowEnd,
                            const int2* __restrict__ pairs, int nNodes, int spmmBlocks,
                            const int* __restrict__ users, const int* __restrict__ items,
                            int* __restrict__ flag2, int batch, int nUser, int markBlocks,
                            const unsigned short* __restrict__ emb0,
                            float* __restrict__ U, float* __restrict__ I) {
    if (blockIdx.x < spmmBlocks) {
        int tid = blockIdx.x * blockDim.x + threadIdx.x;
        int row = tid >> 3;
        int fl  = tid & 7;
        if (row >= nNodes) return;
        spmm_row(curE, nextE, rowPtr, rowEnd, pairs, row, fl);
    } else if (blockIdx.x < spmmBlocks + markBlocks) {
        int tid = (blockIdx.x - spmmBlocks) * blockDim.x + threadIdx.x;
        int idx = tid >> 4;
        int ln  = tid & 15;
        if (idx >= 2 * batch) return;
        int row = (idx < batch) ? users[idx] : (nUser + items[idx - batch]);
        if (ln == 0) flag2[row] = 1;
        int beg = rowPtr[row], end = rowEnd[row];
        for (int j = beg + ln; j < end; j += 16) flag2[pairs[j].x] = 1;
    } else {
        int t = (blockIdx.x - spmmBlocks - markBlocks) * blockDim.x + threadIdx.x;
        if (t >= batch * EMB) return;
        int b = t >> 6, c = t & 63;
        U[t] = bf2f(emb0[users[b] * EMB + c]) * 0.25f;
        I[t] = bf2f(emb0[(nUser + items[b]) * EMB + c]) * 0.25f;
    }
}

// ---------- fused layer 2: flag2 spmm | gather_add(layer-1) ---------------
__global__ void ALGN_l2fuse(const uint4* __restrict__ curE, uint4* __restrict__ nextE,
                            const int* __restrict__ rowPtr, const int* __restrict__ rowEnd,
                            const int2* __restrict__ pairs, const int* __restrict__ flag,
                            int nNodes, int spmmBlocks,
                            const unsigned short* __restrict__ embGA,
                            const int* __restrict__ users, const int* __restrict__ items,
                            float* __restrict__ U, float* __restrict__ I,
                            int batch, int nUser) {
    if (blockIdx.x < spmmBlocks) {
        int tid = blockIdx.x * blockDim.x + threadIdx.x;
        int row = tid >> 3;
        int fl  = tid & 7;
        if (row >= nNodes) return;
        if (!flag[row]) return;
        spmm_row(curE, nextE, rowPtr, rowEnd, pairs, row, fl);
    } else {
        int t = (blockIdx.x - spmmBlocks) * blockDim.x + threadIdx.x;
        if (t >= batch * EMB) return;
        int b = t >> 6, c = t & 63;
        U[t] += bf2f(embGA[users[b] * EMB + c]) * 0.25f;
        I[t] += bf2f(embGA[(nUser + items[b]) * EMB + c]) * 0.25f;
    }
}

// ---------- fused layer 3: batch-list spmm | gather_add(layer-2) ----------
// Rows straight from users/items (dups write identical bytes: benign).
__global__ void ALGN_l3fuse(const uint4* __restrict__ curE, uint4* __restrict__ nextE,
                            const int* __restrict__ rowPtr, const int* __restrict__ rowEnd,
                            const int2* __restrict__ pairs,
                            const int* __restrict__ users, const int* __restrict__ items,
                            int batch, int nUser, int listBlocks,
                            const unsigned short* __restrict__ embGA,
                            float* __restrict__ U, float* __restrict__ I) {
    if (blockIdx.x < listBlocks) {
        int tid = blockIdx.x * blockDim.x + threadIdx.x;
        int idx = tid >> 3;
        int fl  = tid & 7;
        if (idx >= 2 * batch) return;
        int row = (idx < batch) ? users[idx] : (nUser + items[idx - batch]);
        spmm_row(curE, nextE, rowPtr, rowEnd, pairs, row, fl);
    } else {
        int t = (blockIdx.x - listBlocks) * blockDim.x + threadIdx.x;
        if (t >= batch * EMB) return;
        int b = t >> 6, c = t & 63;
        U[t] += bf2f(embGA[users[b] * EMB + c]) * 0.25f;
        I[t] += bf2f(embGA[(nUser + items[b]) * EMB + c]) * 0.25f;
    }
}

// ---------- sigmoid(U @ I^T) with fused layer-3 gather_add on tile load ---
// su/si = accumulated 3 layers + embL3[batch row]*0.25 (bitwise-identical
// f32 math to the separate gather_add it replaces).
__global__ void ALGN_gemm_sigmoid(const float* __restrict__ U, const float* __restrict__ I,
                                  const unsigned short* __restrict__ embL3,
                                  const int* __restrict__ users, const int* __restrict__ items,
                                  float* __restrict__ out, int B, int nUser) {
    __shared__ float su[32][EMB + 1];
    __shared__ float si[32][EMB + 1];
    int tx = threadIdx.x, ty = threadIdx.y;     // 16x16
    int row0 = blockIdx.y * 32, col0 = blockIdx.x * 32;
    int tid = ty * 16 + tx;
    for (int k = tid; k < 32 * EMB; k += 256) {
        int r = k >> 6, c = k & 63;
        int ur = users[row0 + r];
        int ir = items[col0 + r];
        su[r][c] = U[(row0 + r) * EMB + c] + bf2f(embL3[ur * EMB + c]) * 0.25f;
        si[r][c] = I[(col0 + r) * EMB + c] + bf2f(embL3[(nUser + ir) * EMB + c]) * 0.25f;
    }
    __syncthreads();
    float s00 = 0.f, s01 = 0.f, s10 = 0.f, s11 = 0.f;
#pragma unroll
    for (int k = 0; k < EMB; ++k) {
        float a0 = su[2 * ty][k],     a1 = su[2 * ty + 1][k];
        float b0 = si[2 * tx][k],     b1 = si[2 * tx + 1][k];
        s00 += a0 * b0; s01 += a0 * b1;
        s10 += a1 * b0; s11 += a1 * b1;
    }
    int r0 = row0 + 2 * ty, c0 = col0 + 2 * tx;
    out[(size_t)r0 * B + c0]           = 1.f / (1.f + __expf(-s00));
    out[(size_t)r0 * B + c0 + 1]       = 1.f / (1.f + __expf(-s01));
    out[(size_t)(r0 + 1) * B + c0]     = 1.f / (1.f + __expf(-s10));
    out[(size_t)(r0 + 1) * B + c0 + 1] = 1.f / (1.f + __expf(-s11));
}

extern "C" void kernel_launch(void* const* d_in, const int* in_sizes, int n_in,
                              void* d_out, int out_size, void* d_ws, size_t ws_size,
                              hipStream_t stream) {
    const float* user_emb = (const float*)d_in[0];
    const float* item_emb = (const float*)d_in[1];
    const float* adj_vals = (const float*)d_in[2];
    const int*   adj_rows = (const int*)d_in[3];
    const int*   adj_cols = (const int*)d_in[4];
    const int*   users    = (const int*)d_in[5];
    const int*   items    = (const int*)d_in[6];
    float* out = (float*)d_out;

    const int nUserF = in_sizes[0];
    const int nItemF = in_sizes[1];
    const int nEdges = in_sizes[2];
    const int batch  = in_sizes[5];
    const int nUser  = nUserF / EMB;
    const int totalF = nUserF + nItemF;
    const int nNodes = totalF / EMB;
    const int n8     = totalF / 8;
    const int nBuckets = (nNodes + BSZ - 1) / BSZ;   // 293
    // seg rounded to x4 so p2's int4/float4 edge loads are 16B-aligned
    const int seg    = (((nEdges + BP - 1) / BP) + 3) & ~3;   // 980

    unsigned short* embA = (unsigned short*)d_ws;
    unsigned short* embB = embA + totalF;
    float* Ub = (float*)(embB + totalF);
    float* Ib = Ub + (size_t)batch * EMB;
    int2*  pairs = (int2*)(Ib + (size_t)batch * EMB);
    int2*  part  = pairs + (size_t)nBuckets * CAP;
    int*   rowPtr = (int*)(part + (size_t)nBuckets * CAP);
    int*   rowEnd = rowPtr + nNodes;
    int*   blockHist   = rowEnd + nNodes;
    int*   bucketTotal = blockHist + NBMAX * BP;
    int*   flag2 = bucketTotal + NBMAX;

    // ---- 1: fused init | p1 ----
    const int initBlocks = (n8 + 255) / 256;         // covers n8 and nNodes flags
    ALGN_init_p1<<<initBlocks + BP, 256, 0, stream>>>(
        (const float4*)user_emb, (const float4*)item_emb, (uint4*)embA,
        flag2, nNodes, nUserF / 8, n8, initBlocks,
        adj_rows, blockHist, nEdges, seg, nBuckets);

    // ---- 2: scanA (blockHist excl-over-blocks; bucketTotal) ----
    ALGN_scanA<<<nBuckets, 1024, 0, stream>>>(blockHist, bucketTotal);

    // ---- 3: p2 scatter into static CAP regions ----
    ALGN_p2<<<BP, 256, 0, stream>>>(adj_rows, adj_cols, adj_vals,
                                    blockHist, part, nEdges, seg, nBuckets);

    // ---- 4: per-bucket counting sort -> rowPtr/rowEnd/pairs ----
    ALGN_bsort<<<nBuckets, 1024, 0, stream>>>(part, bucketTotal, pairs,
                                              rowPtr, rowEnd, nNodes);

    const int spmmBlocks = (nNodes * 8 + 255) / 256;
    const int markBlocks = (2 * batch * 16 + 255) / 256;
    const int gaBlocks   = (batch * EMB + 255) / 256;
    const int listBlocks = (2 * batch * 8 + 255) / 256;

    // ---- 5: layer-1 full spmm | mark2 | gather_set ----
    ALGN_l1fuse<<<spmmBlocks + markBlocks + gaBlocks, 256, 0, stream>>>(
        (const uint4*)embA, (uint4*)embB, rowPtr, rowEnd, pairs, nNodes, spmmBlocks,
        users, items, flag2, batch, nUser, markBlocks,
        embA, Ub, Ib);

    // ---- 6: layer-2 flag spmm | gather_add(layer-1 = embB) ----
    ALGN_l2fuse<<<spmmBlocks + gaBlocks, 256, 0, stream>>>(
        (const uint4*)embB, (uint4*)embA, rowPtr, rowEnd, pairs, flag2,
        nNodes, spmmBlocks, embB, users, items, Ub, Ib, batch, nUser);

    // ---- 7: layer-3 batch-list spmm | gather_add(layer-2 = embA) ----
    ALGN_l3fuse<<<listBlocks + gaBlocks, 256, 0, stream>>>(
        (const uint4*)embA, (uint4*)embB, rowPtr, rowEnd, pairs,
        users, items, batch, nUser, listBlocks,
        embA, Ub, Ib);

    // ---- 8: gemm + sigmoid with fused layer-3 gather_add ----
    dim3 gg(batch / 32, batch / 32);
    dim3 gb(16, 16);
    ALGN_gemm_sigmoid<<<gg, gb, 0, stream>>>(Ub, Ib, embB, users, items,
                                             out, batch, nUser);
}